// Round 4
// baseline (305.283 us; speedup 1.0000x reference)
//
#include <hip/hip_runtime.h>
#include <hip/hip_bf16.h>

// SAGAN attention block: B=4, C=256, H=W=64 (N=4096).
// Round 4: k_attn = 2-phase double-buffered pipeline (stage t+1 issued before
// compute of t, one barrier/iter), no key-split (256 blocks = 1/CU, merge
// removed), wave-private P buffer, T13 defer-max rescale skip.
// Conv path unchanged (3-pass split-bf16 f,g; fp16 attn path).

typedef short short8 __attribute__((ext_vector_type(8)));
typedef float f32x4 __attribute__((ext_vector_type(4)));
typedef _Float16 f16x8 __attribute__((ext_vector_type(8)));
typedef unsigned short u16;

#define DEV static __device__ __forceinline__
#define MFMA(a, b, c)   __builtin_amdgcn_mfma_f32_16x16x32_bf16(a, b, c, 0, 0, 0)
#define MFMA16(a, b, c) __builtin_amdgcn_mfma_f32_16x16x32_f16(a, b, c, 0, 0, 0)

DEV u16 b16(float x) {
    __hip_bfloat16 h = __float2bfloat16(x);
    return *reinterpret_cast<u16*>(&h);
}
DEV float f16f(u16 u) {
    union { unsigned int ui; float f; } c;
    c.ui = ((unsigned int)u) << 16;
    return c.f;
}
DEV u16 h16(float x) {
    union { _Float16 h; u16 u; } c;
    c.h = (_Float16)x;
    return c.u;
}
DEV short8 ld8(const u16* p) { return *reinterpret_cast<const short8*>(p); }
DEV f16x8 ldh8(const u16* p) { return *reinterpret_cast<const f16x8*>(p); }

// async global->LDS, 16B per lane; dst is wave-uniform base, HW adds lane*16
DEV void gload16(const void* g, void* l) {
    __builtin_amdgcn_global_load_lds(
        (const __attribute__((address_space(1))) unsigned int*)g,
        (__attribute__((address_space(3))) unsigned int*)l, 16, 0, 0);
}

// ---- workspace byte offsets ----
constexpr size_t OFF_WFH = 0;         // 128K bf16 hi
constexpr size_t OFF_WFL = 131072;
constexpr size_t OFF_WGH = 262144;
constexpr size_t OFF_WGL = 393216;
constexpr size_t OFF_WHB = 524288;    // 128K bf16
constexpr size_t OFF_WVB = 655360;    // 128K fp16
constexpr size_t OFF_F   = 1310720;   // 8M fp16 [m][c]   (K source, live through attn)
constexpr size_t OFF_G   = OFF_F + 8388608;    // 8M fp16 [m][c]  (Q source)
constexpr size_t OFF_H   = OFF_G + 8388608;    // 8M fp16 [b][c][n] (V source)
constexpr size_t OFF_XTH = OFF_H + 8388608;    // bf16 [m][c], dead after conv_h
constexpr size_t OFF_XTL = OFF_XTH + 8388608;
constexpr size_t OFF_OT  = OFF_XTH;            // 8M fp16, aliases dead XtH
// high-water mark = OFF_XTL + 8388608 = 43,253,760 bytes

// ---------------- weight prep ----------------
__global__ __launch_bounds__(256) void k_prep_w(
    const float* __restrict__ Wf, const float* __restrict__ Wg,
    const float* __restrict__ Wh, const float* __restrict__ Wv,
    u16* WFH, u16* WFL, u16* WGH, u16* WGL, u16* WHB, u16* WVB) {
    int i = blockIdx.x * 256 + threadIdx.x;
    float fv = Wf[i];
    u16 fh = b16(fv);
    WFH[i] = fh;
    WFL[i] = b16(fv - f16f(fh));
    float gv = Wg[i];
    u16 gh = b16(gv);
    WGH[i] = gh;
    WGL[i] = b16(gv - f16f(gh));
    WHB[i] = b16(Wh[i]);
    WVB[i] = h16(Wv[i]);
}

// ---------------- x transpose + split ----------------
__global__ __launch_bounds__(256) void k_prep_x(const float* __restrict__ x, u16* XtH, u16* XtL) {
    __shared__ float lds[64][65];
    int bid = blockIdx.x;
    int b = bid >> 8, rem = bid & 255, ct = rem >> 6, nt = rem & 63;
    int tid = threadIdx.x;
    int tx = tid & 63, ty = tid >> 6;
    const float* src = x + ((size_t)(b * 256 + ct * 64)) * 4096 + nt * 64;
#pragma unroll
    for (int k = 0; k < 16; ++k) {
        int cl = ty * 16 + k;
        lds[cl][tx] = src[(size_t)cl * 4096 + tx];
    }
    __syncthreads();
    int nl = tid >> 2, cg = tid & 3;
    short8 h0, h1, l0, l1;
#pragma unroll
    for (int j = 0; j < 8; ++j) {
        float v = lds[cg * 16 + j][nl];
        u16 hb = b16(v);
        h0[j] = (short)hb;
        l0[j] = (short)b16(v - f16f(hb));
    }
#pragma unroll
    for (int j = 8; j < 16; ++j) {
        float v = lds[cg * 16 + j][nl];
        u16 hb = b16(v);
        h1[j - 8] = (short)hb;
        l1[j - 8] = (short)b16(v - f16f(hb));
    }
    size_t dst = ((size_t)(b * 4096 + nt * 64 + nl)) * 256 + ct * 64 + cg * 16;
    *reinterpret_cast<short8*>(XtH + dst) = h0;
    *reinterpret_cast<short8*>(XtH + dst + 8) = h1;
    *reinterpret_cast<short8*>(XtL + dst) = l0;
    *reinterpret_cast<short8*>(XtL + dst + 8) = l1;
}

// ---------------- conv f,g: 3-pass split-bf16 MFMA, fp16 out ----------------
__global__ __launch_bounds__(256) void k_conv_fg(
    const u16* __restrict__ XtH, const u16* __restrict__ XtL,
    const u16* __restrict__ WFH, const u16* __restrict__ WFL,
    const u16* __restrict__ WGH, const u16* __restrict__ WGL,
    const float* __restrict__ bf, const float* __restrict__ bg,
    u16* F, u16* G) {
    int bidm = blockIdx.x & 255, bido = blockIdx.x >> 8;
    int w = threadIdx.x >> 6, lane = threadIdx.x & 63, r = lane & 15, g = lane >> 4;
    int m0 = bidm * 64 + w * 16, o0 = bido * 64;
    f32x4 fa[4], ga[4];
#pragma unroll
    for (int i = 0; i < 4; ++i) { fa[i] = {0.f, 0.f, 0.f, 0.f}; ga[i] = {0.f, 0.f, 0.f, 0.f}; }
    const u16* arh = XtH + (size_t)(m0 + r) * 256;
    const u16* arl = XtL + (size_t)(m0 + r) * 256;
#pragma unroll
    for (int ks = 0; ks < 8; ++ks) {
        int k0 = ks * 32 + 8 * g;
        short8 ah = ld8(arh + k0);
        short8 al = ld8(arl + k0);
#pragma unroll
        for (int ot = 0; ot < 4; ++ot) {
            size_t wrow = (size_t)(o0 + ot * 16 + r) * 256 + k0;
            short8 wfh = ld8(WFH + wrow), wfl = ld8(WFL + wrow);
            short8 wgh = ld8(WGH + wrow), wgl = ld8(WGL + wrow);
            fa[ot] = MFMA(ah, wfh, fa[ot]);
            fa[ot] = MFMA(ah, wfl, fa[ot]);
            fa[ot] = MFMA(al, wfh, fa[ot]);
            ga[ot] = MFMA(ah, wgh, ga[ot]);
            ga[ot] = MFMA(ah, wgl, ga[ot]);
            ga[ot] = MFMA(al, wgh, ga[ot]);
        }
    }
#pragma unroll
    for (int ot = 0; ot < 4; ++ot) {
#pragma unroll
        for (int q = 0; q < 4; ++q) {
            int row = m0 + 4 * g + q;
            int col = o0 + ot * 16 + r;
            size_t idx = (size_t)row * 256 + col;
            F[idx] = h16(fa[ot][q] + bf[col]);
            G[idx] = h16(ga[ot][q] + bg[col]);
        }
    }
}

// ---------------- conv h: bf16 MFMA, fp16 out, layout [b][c][n] ----------------
__global__ __launch_bounds__(256) void k_conv_h(
    const u16* __restrict__ WHB, const u16* __restrict__ XtH,
    const float* __restrict__ bh, u16* Hb) {
    int bidn = blockIdx.x & 255, bido = blockIdx.x >> 8;
    int w = threadIdx.x >> 6, lane = threadIdx.x & 63, r = lane & 15, g = lane >> 4;
    int o0 = bido * 64 + w * 16, n0 = bidn * 64;
    f32x4 acc[4];
#pragma unroll
    for (int i = 0; i < 4; ++i) acc[i] = {0.f, 0.f, 0.f, 0.f};
    const u16* arow = WHB + (size_t)(o0 + r) * 256;
#pragma unroll
    for (int ks = 0; ks < 8; ++ks) {
        int k0 = ks * 32 + 8 * g;
        short8 a = ld8(arow + k0);
#pragma unroll
        for (int ntl = 0; ntl < 4; ++ntl) {
            short8 bb = ld8(XtH + (size_t)(n0 + ntl * 16 + r) * 256 + k0);
            acc[ntl] = MFMA(a, bb, acc[ntl]);
        }
    }
#pragma unroll
    for (int ntl = 0; ntl < 4; ++ntl) {
#pragma unroll
        for (int q = 0; q < 4; ++q) {
            int o = o0 + 4 * g + q;
            int nf = n0 + ntl * 16 + r;
            int bb = nf >> 12, n = nf & 4095;
            Hb[((size_t)(bb * 256 + o)) * 4096 + n] = h16(acc[ntl][q] + bh[o]);
        }
    }
}

// ---------------- flash attention: 2-phase pipelined, dbuf LDS, defer-max ----------------
DEV float rmax16(float v) {
    v = fmaxf(v, __shfl_xor(v, 1));
    v = fmaxf(v, __shfl_xor(v, 2));
    v = fmaxf(v, __shfl_xor(v, 4));
    v = fmaxf(v, __shfl_xor(v, 8));
    return v;
}
DEV float rsum16(float v) {
    v += __shfl_xor(v, 1);
    v += __shfl_xor(v, 2);
    v += __shfl_xor(v, 4);
    v += __shfl_xor(v, 8);
    return v;
}

__global__ __launch_bounds__(256, 1) void k_attn(
    const u16* __restrict__ F, const u16* __restrict__ G,
    const u16* __restrict__ Hb, u16* __restrict__ OT) {
    // Double-buffered tiles, XOR-swizzled (byte ^= (row&7)<<4):
    //   K: [64 keys][256 c] fp16 = 32KB each;  V: [256 c][64 keys] fp16 = 32KB each.
    __shared__ u16 Kd[2][16384];
    __shared__ u16 Vd[2][16384];
    __shared__ u16 Pd[4][1280];   // wave-private P[16][72]

    int bid = blockIdx.x;             // 256 blocks = 8 xcd-groups * 32
    int xcd = bid & 7;
    int b = xcd >> 1, half = xcd & 1; // each XCD: one (batch, query-half)
    int jt = bid >> 3;                // 0..31
    int tid = threadIdx.x;
    int w = tid >> 6, lane = tid & 63, r = lane & 15, g = lane >> 4;
    int j0 = half * 2048 + jt * 64 + w * 16;  // wave's 16 queries
    const float L2E = 1.4426950408889634f;

    // Q (g-projection) resident in registers: A-frag rows j=r
    f16x8 Qf[8];
    {
        const u16* q = G + (size_t)(b * 4096 + j0 + r) * 256;
#pragma unroll
        for (int k = 0; k < 8; ++k) Qf[k] = ldh8(q + k * 32 + 8 * g);
    }
    f32x4 O[16];
#pragma unroll
    for (int i = 0; i < 16; ++i) O[i] = {0.f, 0.f, 0.f, 0.f};
    float m[4], l[4];
#pragma unroll
    for (int q = 0; q < 4; ++q) { m[q] = -1e30f; l[q] = 0.f; }

    const char* Fb  = (const char*)(F + (size_t)b * 4096 * 256);   // K base
    const char* Hbb = (const char*)(Hb + (size_t)b * 256 * 4096);  // V base
    u16* Pw = Pd[w];

    // Pre-swizzled per-lane source offsets for staging (dest is linear).
    int koff[8], voff[8];
#pragma unroll
    for (int t = 0; t < 8; ++t) {
        int d = (w * 8 + t) * 1024 + lane * 16;          // dest byte in tile
        koff[t] = d ^ (((d >> 9) & 7) << 4);             // K: row=d>>9 (512B rows)
        int c = d >> 7, kb = d & 127;                    // V: c-row (128B rows)
        voff[t] = (c << 13) + (kb ^ (((c & 7)) << 4));
    }

#define STAGE(nxt, I0)                                                          \
    do {                                                                        \
        const char* kbase = Fb + (size_t)(I0) * 512;                            \
        const char* vbase = Hbb + (size_t)(I0) * 2;                             \
        char* kl = (char*)Kd[nxt];                                              \
        char* vl = (char*)Vd[nxt];                                              \
        _Pragma("unroll") for (int t = 0; t < 8; ++t)                           \
            gload16(kbase + koff[t], kl + (w * 8 + t) * 1024);                  \
        _Pragma("unroll") for (int t = 0; t < 8; ++t)                           \
            gload16(vbase + voff[t], vl + (w * 8 + t) * 1024);                  \
    } while (0)

    STAGE(0, 0);  // prologue

    for (int it = 0; it < 64; ++it) {
        int cur = it & 1;
        __syncthreads();  // drains vmcnt(0): tile `it` ready; prev compute done
        if (it + 1 < 64) STAGE(cur ^ 1, (it + 1) * 64);  // fly under compute

        // ---- QK^T: S'[j][i], B-frags from swizzled K tile ----
        const char* Kl = (const char*)Kd[cur];
        const char* Vl = (const char*)Vd[cur];
        f32x4 s[4];
#pragma unroll
        for (int it2 = 0; it2 < 4; ++it2) s[it2] = {0.f, 0.f, 0.f, 0.f};
#pragma unroll
        for (int it2 = 0; it2 < 4; ++it2) {
            int row = it2 * 16 + r;
            const char* kr = Kl + row * 512;
            int sw = (row & 7) << 4;
#pragma unroll
            for (int k = 0; k < 8; ++k) {
                f16x8 kb = *reinterpret_cast<const f16x8*>(kr + ((k * 64 + 16 * g) ^ sw));
                s[it2] = MFMA16(Qf[k], kb, s[it2]);
            }
        }

        // ---- online softmax (T13 defer-max, THR=8) ----
        float nm[4], grow = -1e30f;
#pragma unroll
        for (int q = 0; q < 4; ++q) {
            float v = fmaxf(fmaxf(s[0][q], s[1][q]), fmaxf(s[2][q], s[3][q]));
            v = rmax16(v);
            nm[q] = v;
            grow = fmaxf(grow, v - m[q]);
        }
        if (__all(grow <= 8.0f)) {
            // skip rescale: keep old max; P bounded by e^8
#pragma unroll
            for (int q = 0; q < 4; ++q) {
                float rs = 0.f;
#pragma unroll
                for (int it2 = 0; it2 < 4; ++it2) {
                    float pv = exp2f((s[it2][q] - m[q]) * L2E);
                    s[it2][q] = pv;
                    rs += pv;
                }
                l[q] += rsum16(rs);
            }
        } else {
            float corr[4];
#pragma unroll
            for (int q = 0; q < 4; ++q) {
                float mn = fmaxf(m[q], nm[q]);
                corr[q] = exp2f((m[q] - mn) * L2E);
                float rs = 0.f;
#pragma unroll
                for (int it2 = 0; it2 < 4; ++it2) {
                    float pv = exp2f((s[it2][q] - mn) * L2E);
                    s[it2][q] = pv;
                    rs += pv;
                }
                l[q] = l[q] * corr[q] + rsum16(rs);
                m[q] = mn;
            }
#pragma unroll
            for (int ct = 0; ct < 16; ++ct) {
                O[ct][0] *= corr[0];
                O[ct][1] *= corr[1];
                O[ct][2] *= corr[2];
                O[ct][3] *= corr[3];
            }
        }

        // ---- P -> wave-private LDS (D-layout), re-read as A-frags ----
#pragma unroll
        for (int it2 = 0; it2 < 4; ++it2) {
#pragma unroll
            for (int q = 0; q < 4; ++q) Pw[(4 * g + q) * 72 + it2 * 16 + r] = h16(s[it2][q]);
        }
        __asm__ volatile("s_waitcnt lgkmcnt(0)" ::: "memory");
        f16x8 pa0 = *reinterpret_cast<const f16x8*>((const char*)Pw + r * 144 + 16 * g);
        f16x8 pa1 = *reinterpret_cast<const f16x8*>((const char*)Pw + r * 144 + 64 + 16 * g);

        // ---- PV: O[j][c] += P[j][i] * V[i][c], B-frags from swizzled V tile ----
#pragma unroll
        for (int ct = 0; ct < 16; ++ct) {
            int c = ct * 16 + r;
            const char* vr = Vl + c * 128;
            int sw = (c & 7) << 4;
            f16x8 v0 = *reinterpret_cast<const f16x8*>(vr + ((16 * g) ^ sw));
            f16x8 v1 = *reinterpret_cast<const f16x8*>(vr + ((64 + 16 * g) ^ sw));
            O[ct] = MFMA16(pa0, v0, O[ct]);
            O[ct] = MFMA16(pa1, v1, O[ct]);
        }
    }
#undef STAGE

    // ---- normalize + store fp16 OT[m][c] ----
    float inv[4];
#pragma unroll
    for (int q = 0; q < 4; ++q) inv[q] = 1.f / l[q];
#pragma unroll
    for (int ct = 0; ct < 16; ++ct) {
#pragma unroll
        for (int q = 0; q < 4; ++q) {
            OT[(size_t)(b * 4096 + j0 + 4 * g + q) * 256 + ct * 16 + r] = h16(O[ct][q] * inv[q]);
        }
    }
}

// ---------------- final conv: fp16 MFMA, f32 out ----------------
__global__ __launch_bounds__(256) void k_conv_out(
    const u16* __restrict__ WVB, const u16* __restrict__ OT,
    const float* __restrict__ bv, float* __restrict__ out) {
    int bidn = blockIdx.x & 255, bido = blockIdx.x >> 8;
    int w = threadIdx.x >> 6, lane = threadIdx.x & 63, r = lane & 15, g = lane >> 4;
    int o0 = bido * 64 + w * 16, n0 = bidn * 64;
    f32x4 acc[4];
#pragma unroll
    for (int i = 0; i < 4; ++i) acc[i] = {0.f, 0.f, 0.f, 0.f};
    const u16* arow = WVB + (size_t)(o0 + r) * 256;
#pragma unroll
    for (int ks = 0; ks < 8; ++ks) {
        int k0 = ks * 32 + 8 * g;
        f16x8 a = ldh8(arow + k0);
#pragma unroll
        for (int ntl = 0; ntl < 4; ++ntl) {
            f16x8 bb = ldh8(OT + (size_t)(n0 + ntl * 16 + r) * 256 + k0);
            acc[ntl] = MFMA16(a, bb, acc[ntl]);
        }
    }
#pragma unroll
    for (int ntl = 0; ntl < 4; ++ntl) {
#pragma unroll
        for (int q = 0; q < 4; ++q) {
            int o = o0 + 4 * g + q;
            int nf = n0 + ntl * 16 + r;
            int bb = nf >> 12, n = nf & 4095;
            out[((size_t)(bb * 256 + o)) * 4096 + n] = acc[ntl][q] + bv[o];
        }
    }
}

extern "C" void kernel_launch(void* const* d_in, const int* in_sizes, int n_in,
                              void* d_out, int out_size, void* d_ws, size_t ws_size,
                              hipStream_t stream) {
    const float* x  = (const float*)d_in[0];
    const float* Wf = (const float*)d_in[1];
    const float* bf = (const float*)d_in[2];
    const float* Wg = (const float*)d_in[3];
    const float* bg = (const float*)d_in[4];
    const float* Wh = (const float*)d_in[5];
    const float* bh = (const float*)d_in[6];
    const float* Wv = (const float*)d_in[7];
    const float* bv = (const float*)d_in[8];
    float* out = (float*)d_out;
    char* ws = (char*)d_ws;

    u16* WFH = (u16*)(ws + OFF_WFH);
    u16* WFL = (u16*)(ws + OFF_WFL);
    u16* WGH = (u16*)(ws + OFF_WGH);
    u16* WGL = (u16*)(ws + OFF_WGL);
    u16* WHB = (u16*)(ws + OFF_WHB);
    u16* WVB = (u16*)(ws + OFF_WVB);
    u16* F   = (u16*)(ws + OFF_F);
    u16* G   = (u16*)(ws + OFF_G);
    u16* H   = (u16*)(ws + OFF_H);
    u16* XTH = (u16*)(ws + OFF_XTH);
    u16* XTL = (u16*)(ws + OFF_XTL);
    u16* OT  = (u16*)(ws + OFF_OT);   // aliases XtH (dead after conv_h)

    k_prep_w<<<256, 256, 0, stream>>>(Wf, Wg, Wh, Wv, WFH, WFL, WGH, WGL, WHB, WVB);
    k_prep_x<<<1024, 256, 0, stream>>>(x, XTH, XTL);
    k_conv_fg<<<1024, 256, 0, stream>>>(XTH, XTL, WFH, WFL, WGH, WGL, bf, bg, F, G);
    k_conv_h<<<1024, 256, 0, stream>>>(WHB, XTH, bh, H);
    k_attn<<<256, 256, 0, stream>>>(F, G, H, OT);
    k_conv_out<<<1024, 256, 0, stream>>>(WVB, OT, bv, out);
}